// Round 6
// baseline (872.975 us; speedup 1.0000x reference)
//
#include <hip/hip_runtime.h>

#define PP 399
#define BB 256

// ---------------------------------------------------------------------------
// Streaming conv+relu+maxpool stage state machine (per (b,p) column).
// Window j covers conv outputs [3j, 3j+9]; emitted when conv t=3j+9 arrives.
// feed computes conv t = nin-2 (stream-relative); preloading xw[1..4] with the
// real history and setting nin=2 lets a machine start mid-stream.
// ---------------------------------------------------------------------------
template<int CIN>
struct Stage {
    float w[3][CIN][5];
    float b[3];
    float xw[CIN][5];
    float m1[3], m2[3], m3[3];
    int nin;
};

template<int CIN>
__device__ __forceinline__ void stage_reset(Stage<CIN>& s) {
#pragma unroll
    for (int ci = 0; ci < CIN; ++ci)
#pragma unroll
        for (int k = 0; k < 5; ++k) s.xw[ci][k] = 0.f;
#pragma unroll
    for (int co = 0; co < 3; ++co) { s.m1[co] = -1e30f; s.m2[co] = -1e30f; s.m3[co] = -1e30f; }
    s.nin = 0;
}

__device__ __forceinline__ void init_s1(Stage<1>& s, const float* __restrict__ Wt,
                                        const float* __restrict__ Bs, int p) {
    const float* wp = Wt + (long)p * 15;   // W1: [P][3][1][5]
#pragma unroll
    for (int co = 0; co < 3; ++co)
#pragma unroll
        for (int k = 0; k < 5; ++k) s.w[co][0][k] = wp[co * 5 + k];
#pragma unroll
    for (int co = 0; co < 3; ++co) s.b[co] = Bs[(long)p * 3 + co];
    stage_reset(s);
}

__device__ __forceinline__ void init_s3(Stage<3>& s, const float* __restrict__ Wt,
                                        const float* __restrict__ Bs, int p) {
    const float* wp = Wt + (long)p * 45;   // W2/3/4: [P][3][3][5]
#pragma unroll
    for (int co = 0; co < 3; ++co)
#pragma unroll
        for (int ci = 0; ci < 3; ++ci)
#pragma unroll
            for (int k = 0; k < 5; ++k)
                s.w[co][ci][k] = wp[(co * 3 + ci) * 5 + k];
#pragma unroll
    for (int co = 0; co < 3; ++co) s.b[co] = Bs[(long)p * 3 + co];
    stage_reset(s);
}

template<int CIN>
__device__ __forceinline__ bool feed(Stage<CIN>& s, const float* in, float* out) {
#pragma unroll
    for (int ci = 0; ci < CIN; ++ci) {
        s.xw[ci][0] = s.xw[ci][1];
        s.xw[ci][1] = s.xw[ci][2];
        s.xw[ci][2] = s.xw[ci][3];
        s.xw[ci][3] = s.xw[ci][4];
        s.xw[ci][4] = in[ci];
    }
    int t = s.nin - 2;
    s.nin++;
    if (t < 0) return false;

    float c[3];
#pragma unroll
    for (int co = 0; co < 3; ++co) {
        float a = s.b[co];
#pragma unroll
        for (int ci = 0; ci < CIN; ++ci)
#pragma unroll
            for (int k = 0; k < 5; ++k)
                a = fmaf(s.xw[ci][k], s.w[co][ci][k], a);
        c[co] = fmaxf(a, 0.f);
    }

    bool emit = false;
    int ph = t % 3;
    if (ph == 0) {
        if (t >= 9) {
#pragma unroll
            for (int co = 0; co < 3; ++co) out[co] = fmaxf(s.m1[co], c[co]);
            emit = true;
        }
#pragma unroll
        for (int co = 0; co < 3; ++co) {
            float a = fmaxf(s.m2[co], c[co]);
            float bb = fmaxf(s.m3[co], c[co]);
            s.m1[co] = a; s.m2[co] = bb; s.m3[co] = c[co];
        }
    } else {
#pragma unroll
        for (int co = 0; co < 3; ++co) {
            s.m1[co] = fmaxf(s.m1[co], c[co]);
            s.m2[co] = fmaxf(s.m2[co], c[co]);
            s.m3[co] = fmaxf(s.m3[co], c[co]);
        }
    }
    return emit;
}

// emission plumbing: stage-1 emission -> stage-2 preload slots 0..3, then feeds
__device__ __forceinline__ void pump12(Stage<1>& s1, Stage<3>& s2, float xval,
                                       int npz, int& ec, int& oc, int j0,
                                       float* __restrict__ o2)
{
    float v1[3], v2[3];
    if (feed(s1, &xval, v1)) {
        int slot = ec + npz;
        ec++;
        if (slot < 4) {
#pragma unroll
            for (int ci = 0; ci < 3; ++ci) s2.xw[ci][1 + slot] = v1[ci];
        } else if (feed(s2, v1, v2)) {
            int j = j0 + oc;
            oc++;
#pragma unroll
            for (int co = 0; co < 3; ++co)
                o2[(long)(co * 37 + j) * PP] = v2[co];
        }
    }
}

// ---------------------------------------------------------------------------
// Fused stage1+stage2, T-segmented: x [256][365][399] -> h2 [256][3][37][399]
// Segment seg computes stage-2 windows [j0, j1).
//   Istart = max(0,3j0-2)  : first stage-1 pooled index produced
//   Iend   = min(3j1+8,118): last one
//   machine-1 conv taus T0=3*Istart .. 3*Iend+9 (feeds x[T0+2 .. 3*Iend+11])
// ---------------------------------------------------------------------------
__global__ __launch_bounds__(64)
void conv_s12_seg(const float* __restrict__ x,
                  const float* __restrict__ W1, const float* __restrict__ b1,
                  const float* __restrict__ W2, const float* __restrict__ b2,
                  float* __restrict__ h2)
{
    int gid = blockIdx.x * 64 + threadIdx.x;
    if (gid >= BB * PP) return;
    int b = gid / PP;
    int p = gid - b * PP;

    int seg = blockIdx.y;
    int j0 = (seg == 0) ? 0 : ((seg == 1) ? 13 : 25);
    int j1 = (seg == 0) ? 13 : ((seg == 1) ? 25 : 37);
    int npz    = (j0 == 0) ? 2 : 0;
    int Istart = (j0 == 0) ? 0 : (3 * j0 - 2);
    int Iend   = min(3 * j1 + 8, 118);
    int T0 = 3 * Istart;

    Stage<1> s1; Stage<3> s2;
    init_s1(s1, W1, b1, p);
    init_s3(s2, W2, b2, p);

    const float* inp = x + (long)b * 365 * PP + p;
    float* o2 = h2 + (long)b * (3 * 37 * PP) + p;

    // machine-1 mid-start: xw[1..4] = x[T0-2 .. T0+1]
#pragma unroll
    for (int k = 0; k < 4; ++k) {
        int t = T0 - 2 + k;
        s1.xw[0][1 + k] = (t >= 0 && t < 365) ? inp[(long)t * PP] : 0.f;
    }
    s1.nin = 2;
    s2.nin = 2;   // first stage-2 feed computes conv t2 = 3*j0

    int ec = 0, oc = 0;
    int nfeed = 3 * (Iend - Istart) + 10;   // always 3*NG + 1
    int NG = nfeed / 3;
    int ibase = T0 + 2;

    float cur[3], nxt[3];
#pragma unroll
    for (int u = 0; u < 3; ++u) {
        int i0 = ibase + u;
        int i1 = ibase + 3 + u;
        cur[u] = (i0 < 365) ? inp[(long)i0 * PP] : 0.f;
        nxt[u] = (i1 < 365) ? inp[(long)i1 * PP] : 0.f;
    }

    for (int g = 0; g < NG; ++g) {
        float nn[3];
#pragma unroll
        for (int u = 0; u < 3; ++u) {
            int i = ibase + 3 * (g + 2) + u;
            nn[u] = (i < 365) ? inp[(long)i * PP] : 0.f;
        }
#pragma unroll
        for (int u = 0; u < 3; ++u)
            pump12(s1, s2, cur[u], npz, ec, oc, j0, o2);
        cur[0] = nxt[0]; cur[1] = nxt[1]; cur[2] = nxt[2];
        nxt[0] = nn[0];  nxt[1] = nn[1];  nxt[2] = nn[2];
    }
    pump12(s1, s2, cur[0], npz, ec, oc, j0, o2);   // remainder feed

    // zero-tail: stage-1 pooled indices beyond Iend (only j1==37 needs idx 119)
    float z[3] = {0.f, 0.f, 0.f};
    float v2[3];
    for (int idx = Iend + 1; idx <= 3 * j1 + 8; ++idx) {
        if (feed(s2, z, v2)) {
            int j = j0 + oc;
            oc++;
#pragma unroll
            for (int co = 0; co < 3; ++co)
                o2[(long)(co * 37 + j) * PP] = v2[co];
        }
    }
}

// ---------------------------------------------------------------------------
// Fused stage3+stage4: h2 [256][3][37][399] -> cbuf[b*1297 + co*399 + p]
// 2-deep input prefetch.
// ---------------------------------------------------------------------------
__global__ __launch_bounds__(64)
void conv_s34(const float* __restrict__ h2,
              const float* __restrict__ W3, const float* __restrict__ b3,
              const float* __restrict__ W4, const float* __restrict__ b4,
              float* __restrict__ cbuf)
{
    int gid = blockIdx.x * 64 + threadIdx.x;
    if (gid >= BB * PP) return;
    int b = gid / PP;
    int p = gid - b * PP;

    Stage<3> s3, s4;
    init_s3(s3, W3, b3, p);
    init_s3(s4, W4, b4, p);

    const float* inp = h2 + (long)b * (3 * 37 * PP) + p;
    float* o4 = cbuf + (long)b * 1297 + p;

    float v3[3], v4[3];
    float z[3] = {0.f, 0.f, 0.f};

    float cur[3], nxt[3];
#pragma unroll
    for (int ci = 0; ci < 3; ++ci) {
        cur[ci] = inp[(long)(ci * 37 + 0) * PP];
        nxt[ci] = inp[(long)(ci * 37 + 1) * PP];
    }

    for (int i = 0; i < 39; ++i) {              // 37 real + 2 pads
        float nn[3];
        int i2 = i + 2;
#pragma unroll
        for (int ci = 0; ci < 3; ++ci)
            nn[ci] = (i2 < 37) ? inp[(long)(ci * 37 + i2) * PP] : 0.f;
        if (feed(s3, cur, v3)) {
            if (feed(s4, v3, v4)) {
#pragma unroll
                for (int co = 0; co < 3; ++co) o4[co * PP] = v4[co];
            }
        }
        cur[0] = nxt[0]; cur[1] = nxt[1]; cur[2] = nxt[2];
        nxt[0] = nn[0];  nxt[1] = nn[1];  nxt[2] = nn[2];
    }
    for (int r = 0; r < 2; ++r) {               // flush s4
        if (feed(s4, z, v4)) {
#pragma unroll
            for (int co = 0; co < 3; ++co) o4[co * PP] = v4[co];
        }
    }
}

// ---------------------------------------------------------------------------
// Split-K GEMM with f32 atomic accumulation. out pre-seeded with bias.
// ---------------------------------------------------------------------------
template<int RELU_A>
__global__ __launch_bounds__(256)
void gemm_atomic(const float* __restrict__ A,
                 const float* __restrict__ Wt,
                 float* __restrict__ out,
                 int K, int N, int lda, int ldo, int kchunk)
{
    __shared__ float As[32][36];
    __shared__ float Bs[32][36];

    int tid = threadIdx.x;
    int ty  = tid >> 3;
    int tx4 = (tid & 7) * 4;
    int c0 = blockIdx.x * 32;
    int m0 = blockIdx.y * 32;
    int k0 = blockIdx.z * kchunk;
    int klim = min(K, k0 + kchunk);

    float4 acc = make_float4(0.f, 0.f, 0.f, 0.f);

    for (int kb = k0; kb < klim; kb += 32) {
#pragma unroll
        for (int j = 0; j < 4; ++j) {
            int kk = kb + tx4 + j;
            float v = (kk < klim) ? A[(long)(m0 + ty) * lda + kk] : 0.f;
            if (RELU_A) v = fmaxf(v, 0.f);
            As[ty][tx4 + j] = v;
        }
#pragma unroll
        for (int j = 0; j < 4; ++j) {
            int kk = kb + ty;
            int c = c0 + tx4 + j;
            Bs[ty][tx4 + j] = (kk < klim && c < N) ? Wt[(long)kk * N + c] : 0.f;
        }
        __syncthreads();
#pragma unroll
        for (int kk = 0; kk < 32; ++kk) {
            float a = As[ty][kk];
            float4 bv = *(const float4*)&Bs[kk][tx4];
            acc.x = fmaf(a, bv.x, acc.x);
            acc.y = fmaf(a, bv.y, acc.y);
            acc.z = fmaf(a, bv.z, acc.z);
            acc.w = fmaf(a, bv.w, acc.w);
        }
        __syncthreads();
    }

    long m = m0 + ty;
    if (c0 + tx4 + 0 < N) atomicAdd(&out[m * ldo + c0 + tx4 + 0], acc.x);
    if (c0 + tx4 + 1 < N) atomicAdd(&out[m * ldo + c0 + tx4 + 1], acc.y);
    if (c0 + tx4 + 2 < N) atomicAdd(&out[m * ldo + c0 + tx4 + 2], acc.z);
    if (c0 + tx4 + 3 < N) atomicAdd(&out[m * ldo + c0 + tx4 + 3], acc.w);
}

__global__ __launch_bounds__(256)
void init_bias(float* __restrict__ e1, const float* __restrict__ lb1,
               float* __restrict__ e2, const float* __restrict__ lb2,
               float* __restrict__ enc2, const float* __restrict__ lb3,
               float* __restrict__ c1, const float* __restrict__ cb1,
               float* __restrict__ c2, const float* __restrict__ cb2,
               float* __restrict__ c3, const float* __restrict__ cb3)
{
    int idx = blockIdx.x * 256 + threadIdx.x;
    if (idx < BB * 700) { e1[idx] = lb1[idx % 700]; return; }
    idx -= BB * 700;
    if (idx < BB * 200) { e2[idx] = lb2[idx % 200]; return; }
    idx -= BB * 200;
    if (idx < BB * 100) { int m = idx / 100, c = idx % 100; enc2[(long)m * 1297 + c] = lb3[c]; return; }
    idx -= BB * 100;
    if (idx < BB * 500) { c1[idx] = cb1[idx % 500]; return; }
    idx -= BB * 500;
    if (idx < BB * 100) { c2[idx] = cb2[idx % 100]; return; }
    idx -= BB * 100;
    if (idx < BB * 20)  { c3[idx] = cb3[idx % 20]; return; }
}

__global__ __launch_bounds__(64)
void final_kernel(const float* __restrict__ c3,
                  const float* __restrict__ fW,
                  const float* __restrict__ fb,
                  float* __restrict__ out)
{
    int m = blockIdx.x * 64 + threadIdx.x;
    if (m >= BB) return;
    float acc = fb[0];
#pragma unroll
    for (int k = 0; k < 20; ++k)
        acc = fmaf(fmaxf(c3[m * 20 + k], 0.f), fW[k], acc);
    out[m] = acc;
}

extern "C" void kernel_launch(void* const* d_in, const int* in_sizes, int n_in,
                              void* d_out, int out_size, void* d_ws, size_t ws_size,
                              hipStream_t stream)
{
    const float* x   = (const float*)d_in[0];
    const float* x2  = (const float*)d_in[1];
    const float* W1  = (const float*)d_in[2];
    const float* b1  = (const float*)d_in[3];
    const float* W2  = (const float*)d_in[4];
    const float* b2  = (const float*)d_in[5];
    const float* W3  = (const float*)d_in[6];
    const float* b3  = (const float*)d_in[7];
    const float* W4  = (const float*)d_in[8];
    const float* b4  = (const float*)d_in[9];
    const float* lW1 = (const float*)d_in[10];
    const float* lb1 = (const float*)d_in[11];
    const float* lW2 = (const float*)d_in[12];
    const float* lb2 = (const float*)d_in[13];
    const float* lW3 = (const float*)d_in[14];
    const float* lb3 = (const float*)d_in[15];
    const float* cW1 = (const float*)d_in[16];
    const float* cb1 = (const float*)d_in[17];
    const float* cW2 = (const float*)d_in[18];
    const float* cb2 = (const float*)d_in[19];
    const float* cW3 = (const float*)d_in[20];
    const float* cb3 = (const float*)d_in[21];
    const float* fW  = (const float*)d_in[22];
    const float* fb  = (const float*)d_in[23];
    float* out = (float*)d_out;

    float* ws = (float*)d_ws;
    const long n_h2   = (long)BB * 3 * 37 * PP;
    const long n_cbuf = (long)BB * 1297;
    float* h2   = ws;
    float* cbuf = h2 + n_h2;
    float* e1   = cbuf + n_cbuf;
    float* e2   = e1 + (long)BB * 700;
    float* c1   = e2 + (long)BB * 200;
    float* c2   = c1 + (long)BB * 500;
    float* c3b  = c2 + (long)BB * 100;

    init_bias<<<1620, 256, 0, stream>>>(e1, lb1, e2, lb2, cbuf + 1197, lb3,
                                        c1, cb1, c2, cb2, c3b, cb3);

    // fused conv chains
    conv_s12_seg<<<dim3(1596, 3), 64, 0, stream>>>(x, W1, b1, W2, b2, h2);
    conv_s34<<<1596, 64, 0, stream>>>(h2, W3, b3, W4, b4, cbuf);

    // enc2 path (ReLU applied on consumer's A-load)
    gemm_atomic<0><<<dim3(22, 8, 6), 256, 0, stream>>>(x2, lW1, e1, 1307, 700, 1307, 700, 256);
    gemm_atomic<1><<<dim3( 7, 8, 6), 256, 0, stream>>>(e1, lW2, e2,  700, 200,  700, 200, 128);
    gemm_atomic<1><<<dim3( 4, 8, 4), 256, 0, stream>>>(e2, lW3, cbuf + 1197, 200, 100, 200, 1297, 64);

    // combined head
    gemm_atomic<0><<<dim3(16, 8, 6), 256, 0, stream>>>(cbuf, cW1, c1, 1297, 500, 1297, 500, 256);
    gemm_atomic<1><<<dim3( 4, 8, 8), 256, 0, stream>>>(c1, cW2, c2, 500, 100, 500, 100, 64);
    gemm_atomic<1><<<dim3( 1, 8, 4), 256, 0, stream>>>(c2, cW3, c3b, 100, 20, 100, 20, 32);

    final_kernel<<<dim3(4), 64, 0, stream>>>(c3b, fW, fb, out);
}

// Round 7
// 231.406 us; speedup vs baseline: 3.7725x; 3.7725x over previous
//
#include <hip/hip_runtime.h>

#define PP 399
#define BB 256

// ---------------------------------------------------------------------------
// Streaming conv+relu+maxpool stage state machine (per (b,p) column).
// Window j covers conv outputs [3j, 3j+9]; emitted when conv t=3j+9 arrives.
// feed computes conv t = nin-2 (stream-relative). A machine can start
// mid-stream by preloading xw (static slots only!) and/or adjusting nin:
// nin = npz-2 makes the first (5-npz) feeds pure FIFO shifts (t<0).
// NOTE: never index xw with a runtime value — that demotes the whole state
// to scratch (HBM) and was a 5x regression in round 6.
// ---------------------------------------------------------------------------
template<int CIN>
struct Stage {
    float w[3][CIN][5];
    float b[3];
    float xw[CIN][5];
    float m1[3], m2[3], m3[3];
    int nin;
};

template<int CIN>
__device__ __forceinline__ void stage_reset(Stage<CIN>& s) {
#pragma unroll
    for (int ci = 0; ci < CIN; ++ci)
#pragma unroll
        for (int k = 0; k < 5; ++k) s.xw[ci][k] = 0.f;
#pragma unroll
    for (int co = 0; co < 3; ++co) { s.m1[co] = -1e30f; s.m2[co] = -1e30f; s.m3[co] = -1e30f; }
    s.nin = 0;
}

__device__ __forceinline__ void init_s1(Stage<1>& s, const float* __restrict__ Wt,
                                        const float* __restrict__ Bs, int p) {
    const float* wp = Wt + (long)p * 15;   // W1: [P][3][1][5]
#pragma unroll
    for (int co = 0; co < 3; ++co)
#pragma unroll
        for (int k = 0; k < 5; ++k) s.w[co][0][k] = wp[co * 5 + k];
#pragma unroll
    for (int co = 0; co < 3; ++co) s.b[co] = Bs[(long)p * 3 + co];
    stage_reset(s);
}

__device__ __forceinline__ void init_s3(Stage<3>& s, const float* __restrict__ Wt,
                                        const float* __restrict__ Bs, int p) {
    const float* wp = Wt + (long)p * 45;   // W2/3/4: [P][3][3][5]
#pragma unroll
    for (int co = 0; co < 3; ++co)
#pragma unroll
        for (int ci = 0; ci < 3; ++ci)
#pragma unroll
            for (int k = 0; k < 5; ++k)
                s.w[co][ci][k] = wp[(co * 3 + ci) * 5 + k];
#pragma unroll
    for (int co = 0; co < 3; ++co) s.b[co] = Bs[(long)p * 3 + co];
    stage_reset(s);
}

template<int CIN>
__device__ __forceinline__ bool feed(Stage<CIN>& s, const float* in, float* out) {
#pragma unroll
    for (int ci = 0; ci < CIN; ++ci) {
        s.xw[ci][0] = s.xw[ci][1];
        s.xw[ci][1] = s.xw[ci][2];
        s.xw[ci][2] = s.xw[ci][3];
        s.xw[ci][3] = s.xw[ci][4];
        s.xw[ci][4] = in[ci];
    }
    int t = s.nin - 2;
    s.nin++;
    if (t < 0) return false;

    float c[3];
#pragma unroll
    for (int co = 0; co < 3; ++co) {
        float a = s.b[co];
#pragma unroll
        for (int ci = 0; ci < CIN; ++ci)
#pragma unroll
            for (int k = 0; k < 5; ++k)
                a = fmaf(s.xw[ci][k], s.w[co][ci][k], a);
        c[co] = fmaxf(a, 0.f);
    }

    bool emit = false;
    int ph = t % 3;
    if (ph == 0) {
        if (t >= 9) {
#pragma unroll
            for (int co = 0; co < 3; ++co) out[co] = fmaxf(s.m1[co], c[co]);
            emit = true;
        }
#pragma unroll
        for (int co = 0; co < 3; ++co) {
            float a = fmaxf(s.m2[co], c[co]);
            float bb = fmaxf(s.m3[co], c[co]);
            s.m1[co] = a; s.m2[co] = bb; s.m3[co] = c[co];
        }
    } else {
#pragma unroll
        for (int co = 0; co < 3; ++co) {
            s.m1[co] = fmaxf(s.m1[co], c[co]);
            s.m2[co] = fmaxf(s.m2[co], c[co]);
            s.m3[co] = fmaxf(s.m3[co], c[co]);
        }
    }
    return emit;
}

// s1 emission -> s2 feed (pure FIFO; s2 warm-up handled by its nin offset)
__device__ __forceinline__ void pump12(Stage<1>& s1, Stage<3>& s2, float xval,
                                       int& oc, int j0, float* __restrict__ o2)
{
    float v1[3], v2[3];
    if (feed(s1, &xval, v1)) {
        if (feed(s2, v1, v2)) {
            int j = j0 + oc;
            oc++;
#pragma unroll
            for (int co = 0; co < 3; ++co)
                o2[(long)(co * 37 + j) * PP] = v2[co];
        }
    }
}

// ---------------------------------------------------------------------------
// Fused stage1+stage2, T-segmented: x [256][365][399] -> h2 [256][3][37][399]
// Segment seg computes stage-2 windows [j0, j1).
//   Istart = (seg==0) ? 0 : 3j0-2  : first stage-1 pooled index produced
//   Iend   = min(3j1+8, 118)       : last one
//   s1 conv taus T0=3*Istart .. 3*Iend+9 (feeds x[T0+2 .. 3*Iend+11])
//   s2.nin = npz-2: first (5-npz) s1 emissions FIFO-shift in; conv fires
//   at global position 3*j0 with window pooled[3j0-2 .. 3j0+2].
// ---------------------------------------------------------------------------
__global__ __launch_bounds__(64)
void conv_s12_seg(const float* __restrict__ x,
                  const float* __restrict__ W1, const float* __restrict__ b1,
                  const float* __restrict__ W2, const float* __restrict__ b2,
                  float* __restrict__ h2)
{
    int gid = blockIdx.x * 64 + threadIdx.x;
    if (gid >= BB * PP) return;
    int b = gid / PP;
    int p = gid - b * PP;

    int seg = blockIdx.y;
    int j0 = (seg == 0) ? 0 : ((seg == 1) ? 13 : 25);
    int j1 = (seg == 0) ? 13 : ((seg == 1) ? 25 : 37);
    int npz    = (seg == 0) ? 2 : 0;
    int Istart = (seg == 0) ? 0 : (3 * j0 - 2);
    int Iend   = min(3 * j1 + 8, 118);
    int T0 = 3 * Istart;

    Stage<1> s1; Stage<3> s2;
    init_s1(s1, W1, b1, p);
    init_s3(s2, W2, b2, p);

    const float* inp = x + (long)b * 365 * PP + p;
    float* o2 = h2 + (long)b * (3 * 37 * PP) + p;

    // s1 mid-start: xw[1..4] = x[T0-2 .. T0+1] (STATIC slot indices)
#pragma unroll
    for (int k = 0; k < 4; ++k) {
        int t = T0 - 2 + k;
        s1.xw[0][1 + k] = (t >= 0 && t < 365) ? inp[(long)t * PP] : 0.f;
    }
    s1.nin = 2;
    s2.nin = npz - 2;

    int oc = 0;
    int nfeed = 3 * (Iend - Istart) + 10;   // == 1 (mod 3)
    int NG = nfeed / 3;
    int ibase = T0 + 2;

    float cur[3], nxt[3];
#pragma unroll
    for (int u = 0; u < 3; ++u) {
        int i0 = ibase + u;
        int i1 = ibase + 3 + u;
        cur[u] = (i0 < 365) ? inp[(long)i0 * PP] : 0.f;
        nxt[u] = (i1 < 365) ? inp[(long)i1 * PP] : 0.f;
    }

    for (int g = 0; g < NG; ++g) {
        float nn[3];
#pragma unroll
        for (int u = 0; u < 3; ++u) {
            int i = ibase + 3 * (g + 2) + u;
            nn[u] = (i < 365) ? inp[(long)i * PP] : 0.f;
        }
#pragma unroll
        for (int u = 0; u < 3; ++u)
            pump12(s1, s2, cur[u], oc, j0, o2);
        cur[0] = nxt[0]; cur[1] = nxt[1]; cur[2] = nxt[2];
        nxt[0] = nn[0];  nxt[1] = nn[1];  nxt[2] = nn[2];
    }
    pump12(s1, s2, cur[0], oc, j0, o2);   // remainder feed

    // zero-tail: stage-1 pooled indices beyond Iend (only j1==37 needs idx 119)
    float z[3] = {0.f, 0.f, 0.f};
    float v2[3];
    for (int idx = Iend + 1; idx <= 3 * j1 + 8; ++idx) {
        if (feed(s2, z, v2)) {
            int j = j0 + oc;
            oc++;
#pragma unroll
            for (int co = 0; co < 3; ++co)
                o2[(long)(co * 37 + j) * PP] = v2[co];
        }
    }
}

// ---------------------------------------------------------------------------
// Fused stage3+stage4: h2 [256][3][37][399] -> cbuf[b*1297 + co*399 + p]
// 2-deep input prefetch.
// ---------------------------------------------------------------------------
__global__ __launch_bounds__(64)
void conv_s34(const float* __restrict__ h2,
              const float* __restrict__ W3, const float* __restrict__ b3,
              const float* __restrict__ W4, const float* __restrict__ b4,
              float* __restrict__ cbuf)
{
    int gid = blockIdx.x * 64 + threadIdx.x;
    if (gid >= BB * PP) return;
    int b = gid / PP;
    int p = gid - b * PP;

    Stage<3> s3, s4;
    init_s3(s3, W3, b3, p);
    init_s3(s4, W4, b4, p);

    const float* inp = h2 + (long)b * (3 * 37 * PP) + p;
    float* o4 = cbuf + (long)b * 1297 + p;

    float v3[3], v4[3];
    float z[3] = {0.f, 0.f, 0.f};

    float cur[3], nxt[3];
#pragma unroll
    for (int ci = 0; ci < 3; ++ci) {
        cur[ci] = inp[(long)(ci * 37 + 0) * PP];
        nxt[ci] = inp[(long)(ci * 37 + 1) * PP];
    }

    for (int i = 0; i < 39; ++i) {              // 37 real + 2 pads
        float nn[3];
        int i2 = i + 2;
#pragma unroll
        for (int ci = 0; ci < 3; ++ci)
            nn[ci] = (i2 < 37) ? inp[(long)(ci * 37 + i2) * PP] : 0.f;
        if (feed(s3, cur, v3)) {
            if (feed(s4, v3, v4)) {
#pragma unroll
                for (int co = 0; co < 3; ++co) o4[co * PP] = v4[co];
            }
        }
        cur[0] = nxt[0]; cur[1] = nxt[1]; cur[2] = nxt[2];
        nxt[0] = nn[0];  nxt[1] = nn[1];  nxt[2] = nn[2];
    }
    for (int r = 0; r < 2; ++r) {               // flush s4
        if (feed(s4, z, v4)) {
#pragma unroll
            for (int co = 0; co < 3; ++co) o4[co * PP] = v4[co];
        }
    }
}

// ---------------------------------------------------------------------------
// Split-K GEMM with f32 atomic accumulation. out pre-seeded with bias.
// ---------------------------------------------------------------------------
template<int RELU_A>
__global__ __launch_bounds__(256)
void gemm_atomic(const float* __restrict__ A,
                 const float* __restrict__ Wt,
                 float* __restrict__ out,
                 int K, int N, int lda, int ldo, int kchunk)
{
    __shared__ float As[32][36];
    __shared__ float Bs[32][36];

    int tid = threadIdx.x;
    int ty  = tid >> 3;
    int tx4 = (tid & 7) * 4;
    int c0 = blockIdx.x * 32;
    int m0 = blockIdx.y * 32;
    int k0 = blockIdx.z * kchunk;
    int klim = min(K, k0 + kchunk);

    float4 acc = make_float4(0.f, 0.f, 0.f, 0.f);

    for (int kb = k0; kb < klim; kb += 32) {
#pragma unroll
        for (int j = 0; j < 4; ++j) {
            int kk = kb + tx4 + j;
            float v = (kk < klim) ? A[(long)(m0 + ty) * lda + kk] : 0.f;
            if (RELU_A) v = fmaxf(v, 0.f);
            As[ty][tx4 + j] = v;
        }
#pragma unroll
        for (int j = 0; j < 4; ++j) {
            int kk = kb + ty;
            int c = c0 + tx4 + j;
            Bs[ty][tx4 + j] = (kk < klim && c < N) ? Wt[(long)kk * N + c] : 0.f;
        }
        __syncthreads();
#pragma unroll
        for (int kk = 0; kk < 32; ++kk) {
            float a = As[ty][kk];
            float4 bv = *(const float4*)&Bs[kk][tx4];
            acc.x = fmaf(a, bv.x, acc.x);
            acc.y = fmaf(a, bv.y, acc.y);
            acc.z = fmaf(a, bv.z, acc.z);
            acc.w = fmaf(a, bv.w, acc.w);
        }
        __syncthreads();
    }

    long m = m0 + ty;
    if (c0 + tx4 + 0 < N) atomicAdd(&out[m * ldo + c0 + tx4 + 0], acc.x);
    if (c0 + tx4 + 1 < N) atomicAdd(&out[m * ldo + c0 + tx4 + 1], acc.y);
    if (c0 + tx4 + 2 < N) atomicAdd(&out[m * ldo + c0 + tx4 + 2], acc.z);
    if (c0 + tx4 + 3 < N) atomicAdd(&out[m * ldo + c0 + tx4 + 3], acc.w);
}

__global__ __launch_bounds__(256)
void init_bias(float* __restrict__ e1, const float* __restrict__ lb1,
               float* __restrict__ e2, const float* __restrict__ lb2,
               float* __restrict__ enc2, const float* __restrict__ lb3,
               float* __restrict__ c1, const float* __restrict__ cb1,
               float* __restrict__ c2, const float* __restrict__ cb2,
               float* __restrict__ c3, const float* __restrict__ cb3)
{
    int idx = blockIdx.x * 256 + threadIdx.x;
    if (idx < BB * 700) { e1[idx] = lb1[idx % 700]; return; }
    idx -= BB * 700;
    if (idx < BB * 200) { e2[idx] = lb2[idx % 200]; return; }
    idx -= BB * 200;
    if (idx < BB * 100) { int m = idx / 100, c = idx % 100; enc2[(long)m * 1297 + c] = lb3[c]; return; }
    idx -= BB * 100;
    if (idx < BB * 500) { c1[idx] = cb1[idx % 500]; return; }
    idx -= BB * 500;
    if (idx < BB * 100) { c2[idx] = cb2[idx % 100]; return; }
    idx -= BB * 100;
    if (idx < BB * 20)  { c3[idx] = cb3[idx % 20]; return; }
}

__global__ __launch_bounds__(64)
void final_kernel(const float* __restrict__ c3,
                  const float* __restrict__ fW,
                  const float* __restrict__ fb,
                  float* __restrict__ out)
{
    int m = blockIdx.x * 64 + threadIdx.x;
    if (m >= BB) return;
    float acc = fb[0];
#pragma unroll
    for (int k = 0; k < 20; ++k)
        acc = fmaf(fmaxf(c3[m * 20 + k], 0.f), fW[k], acc);
    out[m] = acc;
}

extern "C" void kernel_launch(void* const* d_in, const int* in_sizes, int n_in,
                              void* d_out, int out_size, void* d_ws, size_t ws_size,
                              hipStream_t stream)
{
    const float* x   = (const float*)d_in[0];
    const float* x2  = (const float*)d_in[1];
    const float* W1  = (const float*)d_in[2];
    const float* b1  = (const float*)d_in[3];
    const float* W2  = (const float*)d_in[4];
    const float* b2  = (const float*)d_in[5];
    const float* W3  = (const float*)d_in[6];
    const float* b3  = (const float*)d_in[7];
    const float* W4  = (const float*)d_in[8];
    const float* b4  = (const float*)d_in[9];
    const float* lW1 = (const float*)d_in[10];
    const float* lb1 = (const float*)d_in[11];
    const float* lW2 = (const float*)d_in[12];
    const float* lb2 = (const float*)d_in[13];
    const float* lW3 = (const float*)d_in[14];
    const float* lb3 = (const float*)d_in[15];
    const float* cW1 = (const float*)d_in[16];
    const float* cb1 = (const float*)d_in[17];
    const float* cW2 = (const float*)d_in[18];
    const float* cb2 = (const float*)d_in[19];
    const float* cW3 = (const float*)d_in[20];
    const float* cb3 = (const float*)d_in[21];
    const float* fW  = (const float*)d_in[22];
    const float* fb  = (const float*)d_in[23];
    float* out = (float*)d_out;

    float* ws = (float*)d_ws;
    const long n_h2   = (long)BB * 3 * 37 * PP;
    const long n_cbuf = (long)BB * 1297;
    float* h2   = ws;
    float* cbuf = h2 + n_h2;
    float* e1   = cbuf + n_cbuf;
    float* e2   = e1 + (long)BB * 700;
    float* c1   = e2 + (long)BB * 200;
    float* c2   = c1 + (long)BB * 500;
    float* c3b  = c2 + (long)BB * 100;

    init_bias<<<1620, 256, 0, stream>>>(e1, lb1, e2, lb2, cbuf + 1197, lb3,
                                        c1, cb1, c2, cb2, c3b, cb3);

    // fused conv chains
    conv_s12_seg<<<dim3(1596, 3), 64, 0, stream>>>(x, W1, b1, W2, b2, h2);
    conv_s34<<<1596, 64, 0, stream>>>(h2, W3, b3, W4, b4, cbuf);

    // enc2 path (ReLU applied on consumer's A-load)
    gemm_atomic<0><<<dim3(22, 8, 6), 256, 0, stream>>>(x2, lW1, e1, 1307, 700, 1307, 700, 256);
    gemm_atomic<1><<<dim3( 7, 8, 6), 256, 0, stream>>>(e1, lW2, e2,  700, 200,  700, 200, 128);
    gemm_atomic<1><<<dim3( 4, 8, 4), 256, 0, stream>>>(e2, lW3, cbuf + 1197, 200, 100, 200, 1297, 64);

    // combined head
    gemm_atomic<0><<<dim3(16, 8, 6), 256, 0, stream>>>(cbuf, cW1, c1, 1297, 500, 1297, 500, 256);
    gemm_atomic<1><<<dim3( 4, 8, 8), 256, 0, stream>>>(c1, cW2, c2, 500, 100, 500, 100, 64);
    gemm_atomic<1><<<dim3( 1, 8, 4), 256, 0, stream>>>(c2, cW3, c3b, 100, 20, 100, 20, 32);

    final_kernel<<<dim3(4), 64, 0, stream>>>(c3b, fW, fb, out);
}